// Round 5
// baseline (221.443 us; speedup 1.0000x reference)
//
#include <hip/hip_runtime.h>
#include <math.h>

#define BATCH 8
#define FDIM  64
#define NDIM  2048
#define MTOT  (BATCH * FDIM * NDIM)
#define SIGMA 2.0f
#define LOG2E 1.4426950408889634f

#define COLSQ_N (BATCH * NDIM)             // 16384 colsq floats
#define NPREP   256                        // prep block count
#define PSUM_OFF (COLSQ_N)                 // 256 per-block sums
#define PSQ_OFF  (COLSQ_N + NPREP)         // 256 per-block sumsqs
#define EMBT_OFF (COLSQ_N + 2 * NPREP)     // bf16 embT starts (byte 67584, 64B aligned)

typedef __attribute__((ext_vector_type(8))) short bf16x8;
typedef __attribute__((ext_vector_type(4))) float f32x4;

static __device__ inline unsigned short f2bf(float x) {
    unsigned int u = __float_as_uint(x);
    return (unsigned short)((u + 0x7fffu + ((u >> 16) & 1u)) >> 16);   // RTNE
}

// prep: 256 blocks x 1 wave, one column per thread. Produces:
//   colsq[b*NDIM+n], per-block partial (sum,sumsq) — no atomics, no memset —
//   and bf16 embT[b][n][f] for 16B-coalesced GEMM staging.
__global__ __launch_bounds__(64) void prep_kernel(
        const float* __restrict__ emb, float* __restrict__ ws) {
    const int blk = blockIdx.x;
    const int b = blk >> 5;
    const int n = ((blk & 31) << 6) + threadIdx.x;
    const float* p = emb + (size_t)b * FDIM * NDIM + n;
    unsigned short* dst = (unsigned short*)(ws + EMBT_OFF) + (size_t)(b * NDIM + n) * FDIM;

    float s = 0.f, q = 0.f;
#pragma unroll
    for (int f0 = 0; f0 < FDIM; f0 += 8) {
        unsigned int wv[4];
#pragma unroll
        for (int j = 0; j < 4; ++j) {
            float a = p[(size_t)(f0 + 2 * j) * NDIM];
            float c = p[(size_t)(f0 + 2 * j + 1) * NDIM];
            s += a + c;
            q += a * a + c * c;
            wv[j] = (unsigned)f2bf(a) | ((unsigned)f2bf(c) << 16);
        }
        *(uint4*)(dst + f0) = make_uint4(wv[0], wv[1], wv[2], wv[3]);
    }
    ws[b * NDIM + n] = q;

#pragma unroll
    for (int off = 32; off > 0; off >>= 1) {
        s += __shfl_down(s, off, 64);
        q += __shfl_down(q, off, 64);
    }
    if (threadIdx.x == 0) {
        ws[PSUM_OFF + blk] = s;
        ws[PSQ_OFF + blk] = q;
    }
}

// gauss: 128x128 tile/block, bf16 MFMA 16x16x32 with SWAPPED operands so the
// C/D regs span m (columns) -> dwordx4 coalesced stores. Reduces the 256
// prep partials in-block (one barrier covers staging + reduction).
// This round (isolated diff vs the R4-verified kernel): per-(i,j)
// interleaved epilogue — 16 independent MFMA->exp->store chains instead of
// compute-then-burst — and nontemporal output stores (write-once data,
// skip L2 retention). exp2f/LOG2E fold retained (verified neutral, keeps
// the epilogue at 2 fma + 1 v_exp_f32 per element).
__global__ __launch_bounds__(256) void gauss_mfma_kernel(
        const float* __restrict__ ws, float* __restrict__ out) {
    __shared__ unsigned short At[128 * 64];
    __shared__ unsigned short Bt[128 * 64];
    __shared__ float qs[256];     // raw colsq for the n-range (0..127) and m-range (128..255)
    __shared__ float red[8];      // 4 wave sums, 4 wave sumsqs

    const int b = blockIdx.z;
    const int n0 = blockIdx.y * 128, m0 = blockIdx.x * 128;
    const int t = threadIdx.x;
    const unsigned short* embT = (const unsigned short*)(ws + EMBT_OFF);
    const unsigned short* baseA = embT + (size_t)(b * NDIM + n0) * FDIM;
    const unsigned short* baseB = embT + (size_t)(b * NDIM + m0) * FDIM;

    // in-block reduction of prep partials (replaces memset+atomics)
    {
        float s = ws[PSUM_OFF + t];
        float q = ws[PSQ_OFF + t];
#pragma unroll
        for (int off = 32; off > 0; off >>= 1) {
            s += __shfl_down(s, off, 64);
            q += __shfl_down(q, off, 64);
        }
        if ((t & 63) == 0) { red[t >> 6] = s; red[4 + (t >> 6)] = q; }
    }

    // stage both tiles, XOR-swizzled LDS chunks (conflict-free b128 reads)
    {
        const int row = t >> 3, c = t & 7;
#pragma unroll
        for (int it = 0; it < 4; ++it) {
            int r = row + it * 32;
            int slot = c ^ (r & 7);
            *(float4*)&At[r * 64 + slot * 8] = *(const float4*)(baseA + r * 64 + c * 8);
            *(float4*)&Bt[r * 64 + slot * 8] = *(const float4*)(baseB + r * 64 + c * 8);
        }
        qs[t] = (t < 128) ? ws[b * NDIM + n0 + t] : ws[b * NDIM + m0 + (t - 128)];
    }
    __syncthreads();

    const int lane = t & 63;
    const int w = t >> 6;
    const int wn = (w & 1) * 64, wm = (w >> 1) * 64;
    const int mrow = lane & 15;
    const int quad = lane >> 4;

    // load all 16 fragments up front (8 A-side, 8 B-side; 64 VGPRs)
    bf16x8 af[2][4], bv[2][4];
#pragma unroll
    for (int ks = 0; ks < 2; ++ks) {
#pragma unroll
        for (int i = 0; i < 4; ++i) {
            int ra = wn + i * 16 + mrow;
            int ca = (ks * 4 + quad) ^ (ra & 7);
            af[ks][i] = *(bf16x8*)&At[ra * 64 + ca * 8];
            int rb = wm + i * 16 + mrow;
            int cb = (ks * 4 + quad) ^ (rb & 7);
            bv[ks][i] = *(bf16x8*)&Bt[rb * 64 + cb * 8];
        }
    }

    // finish the global reduction redundantly per thread (LDS broadcast reads)
    const float S = red[0] + red[1] + red[2] + red[3];
    const float Q = red[4] + red[5] + red[6] + red[7];
    const float M = (float)MTOT;
    const float var = (Q - S * S / M) / (M - 1.0f);
    const float sc = LOG2E / (var * (float)FDIM * SIGMA);   // log2e folded in
    const float s2 = 2.0f * sc;

    // hoist the per-row/-col bias terms
    f32x4 qm4[4];
    float qnt[4];
#pragma unroll
    for (int j = 0; j < 4; ++j)
        qm4[j] = *(f32x4*)&qs[128 + wm + j * 16 + quad * 4];
#pragma unroll
    for (int i = 0; i < 4; ++i)
        qnt[i] = -sc * qs[wn + i * 16 + mrow];

    const size_t obase = (size_t)b * NDIM * NDIM;
#pragma unroll
    for (int i = 0; i < 4; ++i) {
        const int n = wn + i * 16 + mrow;                 // n index (lane&15 side)
#pragma unroll
        for (int j = 0; j < 4; ++j) {
            const int mbase = wm + j * 16 + quad * 4;     // m index (reg side)
            f32x4 acc = {};
            // swapped: D rows <- bv (m side), D cols <- af (n side)
            acc = __builtin_amdgcn_mfma_f32_16x16x32_bf16(bv[0][j], af[0][i], acc, 0, 0, 0);
            acc = __builtin_amdgcn_mfma_f32_16x16x32_bf16(bv[1][j], af[1][i], acc, 0, 0, 0);
            f32x4 o;
            o[0] = exp2f(fmaf(s2, acc[0], fmaf(-sc, qm4[j][0], qnt[i])));
            o[1] = exp2f(fmaf(s2, acc[1], fmaf(-sc, qm4[j][1], qnt[i])));
            o[2] = exp2f(fmaf(s2, acc[2], fmaf(-sc, qm4[j][2], qnt[i])));
            o[3] = exp2f(fmaf(s2, acc[3], fmaf(-sc, qm4[j][3], qnt[i])));
            __builtin_nontemporal_store(
                o, (f32x4*)&out[obase + (size_t)(n0 + n) * NDIM + (m0 + mbase)]);
        }
    }
}

extern "C" void kernel_launch(void* const* d_in, const int* in_sizes, int n_in,
                              void* d_out, int out_size, void* d_ws, size_t ws_size,
                              hipStream_t stream) {
    // d_in[0] = adj_in (unused by reference). d_in[1] = emb_in [8,64,2048] fp32.
    const float* emb = (const float*)d_in[1];
    float* out = (float*)d_out;
    float* ws  = (float*)d_ws;

    prep_kernel<<<NPREP, 64, 0, stream>>>(emb, ws);

    dim3 grid(NDIM / 128, NDIM / 128, BATCH);
    gauss_mfma_kernel<<<grid, 256, 0, stream>>>(ws, out);
}

// Round 6
// 211.466 us; speedup vs baseline: 1.0472x; 1.0472x over previous
//
#include <hip/hip_runtime.h>
#include <math.h>

#define BATCH 8
#define FDIM  64
#define NDIM  2048
#define MTOT  (BATCH * FDIM * NDIM)
#define SIGMA 2.0f
#define LOG2E 1.4426950408889634f

#define COLSQ_N (BATCH * NDIM)             // 16384 colsq floats
#define NPREP   256                        // prep block count
#define PSUM_OFF (COLSQ_N)                 // 256 per-block sums
#define PSQ_OFF  (COLSQ_N + NPREP)         // 256 per-block sumsqs
#define EMBT_OFF (COLSQ_N + 2 * NPREP)     // bf16 embT starts (byte 67584, 64B aligned)

typedef __attribute__((ext_vector_type(8))) short bf16x8;
typedef __attribute__((ext_vector_type(4))) float f32x4;

static __device__ inline unsigned short f2bf(float x) {
    unsigned int u = __float_as_uint(x);
    return (unsigned short)((u + 0x7fffu + ((u >> 16) & 1u)) >> 16);   // RTNE
}

// prep: 256 blocks x 1 wave, one column per thread. Produces:
//   colsq[b*NDIM+n], per-block partial (sum,sumsq) — no atomics, no memset —
//   and bf16 embT[b][n][f] for 16B-coalesced GEMM staging.
__global__ __launch_bounds__(64) void prep_kernel(
        const float* __restrict__ emb, float* __restrict__ ws) {
    const int blk = blockIdx.x;
    const int b = blk >> 5;
    const int n = ((blk & 31) << 6) + threadIdx.x;
    const float* p = emb + (size_t)b * FDIM * NDIM + n;
    unsigned short* dst = (unsigned short*)(ws + EMBT_OFF) + (size_t)(b * NDIM + n) * FDIM;

    float s = 0.f, q = 0.f;
#pragma unroll
    for (int f0 = 0; f0 < FDIM; f0 += 8) {
        unsigned int wv[4];
#pragma unroll
        for (int j = 0; j < 4; ++j) {
            float a = p[(size_t)(f0 + 2 * j) * NDIM];
            float c = p[(size_t)(f0 + 2 * j + 1) * NDIM];
            s += a + c;
            q += a * a + c * c;
            wv[j] = (unsigned)f2bf(a) | ((unsigned)f2bf(c) << 16);
        }
        *(uint4*)(dst + f0) = make_uint4(wv[0], wv[1], wv[2], wv[3]);
    }
    ws[b * NDIM + n] = q;

#pragma unroll
    for (int off = 32; off > 0; off >>= 1) {
        s += __shfl_down(s, off, 64);
        q += __shfl_down(q, off, 64);
    }
    if (threadIdx.x == 0) {
        ws[PSUM_OFF + blk] = s;
        ws[PSQ_OFF + blk] = q;
    }
}

// gauss: 128x128 tile/block, bf16 MFMA 16x16x32 with SWAPPED operands so the
// C/D regs span m (columns) -> dwordx4 coalesced stores. Reduces the 256
// prep partials in-block (one barrier covers staging + reduction).
// R6 isolation: KEEP the per-(i,j) interleaved epilogue from R5, DROP the
// nontemporal stores (suspected culprit: nt defeats L2 write-combining of
// this layout's 16x64B scattered wave-stores -> partial-line HBM writes).
__global__ __launch_bounds__(256) void gauss_mfma_kernel(
        const float* __restrict__ ws, float* __restrict__ out) {
    __shared__ unsigned short At[128 * 64];
    __shared__ unsigned short Bt[128 * 64];
    __shared__ float qs[256];     // raw colsq for the n-range (0..127) and m-range (128..255)
    __shared__ float red[8];      // 4 wave sums, 4 wave sumsqs

    const int b = blockIdx.z;
    const int n0 = blockIdx.y * 128, m0 = blockIdx.x * 128;
    const int t = threadIdx.x;
    const unsigned short* embT = (const unsigned short*)(ws + EMBT_OFF);
    const unsigned short* baseA = embT + (size_t)(b * NDIM + n0) * FDIM;
    const unsigned short* baseB = embT + (size_t)(b * NDIM + m0) * FDIM;

    // in-block reduction of prep partials (replaces memset+atomics)
    {
        float s = ws[PSUM_OFF + t];
        float q = ws[PSQ_OFF + t];
#pragma unroll
        for (int off = 32; off > 0; off >>= 1) {
            s += __shfl_down(s, off, 64);
            q += __shfl_down(q, off, 64);
        }
        if ((t & 63) == 0) { red[t >> 6] = s; red[4 + (t >> 6)] = q; }
    }

    // stage both tiles, XOR-swizzled LDS chunks (conflict-free b128 reads)
    {
        const int row = t >> 3, c = t & 7;
#pragma unroll
        for (int it = 0; it < 4; ++it) {
            int r = row + it * 32;
            int slot = c ^ (r & 7);
            *(float4*)&At[r * 64 + slot * 8] = *(const float4*)(baseA + r * 64 + c * 8);
            *(float4*)&Bt[r * 64 + slot * 8] = *(const float4*)(baseB + r * 64 + c * 8);
        }
        qs[t] = (t < 128) ? ws[b * NDIM + n0 + t] : ws[b * NDIM + m0 + (t - 128)];
    }
    __syncthreads();

    const int lane = t & 63;
    const int w = t >> 6;
    const int wn = (w & 1) * 64, wm = (w >> 1) * 64;
    const int mrow = lane & 15;
    const int quad = lane >> 4;

    // load all 16 fragments up front (8 A-side, 8 B-side; 64 VGPRs)
    bf16x8 af[2][4], bv[2][4];
#pragma unroll
    for (int ks = 0; ks < 2; ++ks) {
#pragma unroll
        for (int i = 0; i < 4; ++i) {
            int ra = wn + i * 16 + mrow;
            int ca = (ks * 4 + quad) ^ (ra & 7);
            af[ks][i] = *(bf16x8*)&At[ra * 64 + ca * 8];
            int rb = wm + i * 16 + mrow;
            int cb = (ks * 4 + quad) ^ (rb & 7);
            bv[ks][i] = *(bf16x8*)&Bt[rb * 64 + cb * 8];
        }
    }

    // finish the global reduction redundantly per thread (LDS broadcast reads)
    const float S = red[0] + red[1] + red[2] + red[3];
    const float Q = red[4] + red[5] + red[6] + red[7];
    const float M = (float)MTOT;
    const float var = (Q - S * S / M) / (M - 1.0f);
    const float sc = LOG2E / (var * (float)FDIM * SIGMA);   // log2e folded in
    const float s2 = 2.0f * sc;

    // hoist the per-row/-col bias terms
    f32x4 qm4[4];
    float qnt[4];
#pragma unroll
    for (int j = 0; j < 4; ++j)
        qm4[j] = *(f32x4*)&qs[128 + wm + j * 16 + quad * 4];
#pragma unroll
    for (int i = 0; i < 4; ++i)
        qnt[i] = -sc * qs[wn + i * 16 + mrow];

    const size_t obase = (size_t)b * NDIM * NDIM;
#pragma unroll
    for (int i = 0; i < 4; ++i) {
        const int n = wn + i * 16 + mrow;                 // n index (lane&15 side)
#pragma unroll
        for (int j = 0; j < 4; ++j) {
            const int mbase = wm + j * 16 + quad * 4;     // m index (reg side)
            f32x4 acc = {};
            // swapped: D rows <- bv (m side), D cols <- af (n side)
            acc = __builtin_amdgcn_mfma_f32_16x16x32_bf16(bv[0][j], af[0][i], acc, 0, 0, 0);
            acc = __builtin_amdgcn_mfma_f32_16x16x32_bf16(bv[1][j], af[1][i], acc, 0, 0, 0);
            f32x4 o;
            o[0] = exp2f(fmaf(s2, acc[0], fmaf(-sc, qm4[j][0], qnt[i])));
            o[1] = exp2f(fmaf(s2, acc[1], fmaf(-sc, qm4[j][1], qnt[i])));
            o[2] = exp2f(fmaf(s2, acc[2], fmaf(-sc, qm4[j][2], qnt[i])));
            o[3] = exp2f(fmaf(s2, acc[3], fmaf(-sc, qm4[j][3], qnt[i])));
            *(f32x4*)&out[obase + (size_t)(n0 + n) * NDIM + (m0 + mbase)] = o;
        }
    }
}

extern "C" void kernel_launch(void* const* d_in, const int* in_sizes, int n_in,
                              void* d_out, int out_size, void* d_ws, size_t ws_size,
                              hipStream_t stream) {
    // d_in[0] = adj_in (unused by reference). d_in[1] = emb_in [8,64,2048] fp32.
    const float* emb = (const float*)d_in[1];
    float* out = (float*)d_out;
    float* ws  = (float*)d_ws;

    prep_kernel<<<NPREP, 64, 0, stream>>>(emb, ws);

    dim3 grid(NDIM / 128, NDIM / 128, BATCH);
    gauss_mfma_kernel<<<grid, 256, 0, stream>>>(ws, out);
}